// Round 1
// baseline (508.167 us; speedup 1.0000x reference)
//
#include <hip/hip_runtime.h>
#include <cstdint>
#include <cstring>

// ---------------------------------------------------------------------------
// JAX PRNG variant switch.
//   1 = jax_threefry_partitionable=True  (default in JAX >= 0.4.36)
//   0 = legacy/original threefry random-bits + split
// If the bench fails with large Output-1 (I) errors, flip this to 0.
// ---------------------------------------------------------------------------
#define JAX_PARTITIONABLE 1

#define B_ 1024
#define P_ 512
#define K_ 128
#define MAXC 76
#define NSCORE 524288ull     // B*P
#define NRAND  67108864ull   // B*P*K
#define OFF_I  ((size_t)B_ * P_ * K_)          // 67108864
#define OFF_MT (OFF_I + (size_t)B_ * MAXC)     // + 77824

// ---------------- Threefry2x32 (exact JAX schedule) ----------------
__host__ __device__ inline uint32_t rotl32(uint32_t v, int d) {
    return (v << d) | (v >> (32 - d));
}

__host__ __device__ inline void tf2x32(uint32_t k0, uint32_t k1,
                                       uint32_t x0, uint32_t x1,
                                       uint32_t& o0, uint32_t& o1) {
    uint32_t ks2 = k0 ^ k1 ^ 0x1BD11BDAu;
    x0 += k0; x1 += k1;
#define TF_R(r) { x0 += x1; x1 = rotl32(x1, (r)); x1 ^= x0; }
    TF_R(13) TF_R(15) TF_R(26) TF_R(6)
    x0 += k1;  x1 += ks2 + 1u;
    TF_R(17) TF_R(29) TF_R(16) TF_R(24)
    x0 += ks2; x1 += k0 + 2u;
    TF_R(13) TF_R(15) TF_R(26) TF_R(6)
    x0 += k0;  x1 += k1 + 3u;
    TF_R(17) TF_R(29) TF_R(16) TF_R(24)
    x0 += k1;  x1 += ks2 + 4u;
    TF_R(13) TF_R(15) TF_R(26) TF_R(6)
    x0 += ks2; x1 += k0 + 5u;
#undef TF_R
    o0 = x0; o1 = x1;
}

// random_bits element i of a length-n uint32 array (n even in all our uses)
__host__ __device__ inline uint32_t jax_bits(uint32_t k0, uint32_t k1,
                                             uint64_t i, uint64_t n) {
#if JAX_PARTITIONABLE
    (void)n;
    uint32_t o0, o1;
    tf2x32(k0, k1, (uint32_t)(i >> 32), (uint32_t)i, o0, o1);
    return o0 ^ o1;
#else
    uint64_t half = n >> 1;
    uint32_t o0, o1;
    if (i < half) { tf2x32(k0, k1, (uint32_t)i, (uint32_t)(i + half), o0, o1); return o0; }
    tf2x32(k0, k1, (uint32_t)(i - half), (uint32_t)i, o0, o1); return o1;
#endif
}

__device__ inline float u01(uint32_t bits) {
    // jax.random.uniform f32: bitcast((bits>>9)|0x3F800000) - 1.0
    return __uint_as_float((bits >> 9) | 0x3F800000u) - 1.0f;
}

// ---------------- Kernel 1: mask_type[i] via rank of sort_keys[i] ----------
// perm = stable sort of arange(1024) keyed by sort_keys; mask_type[i] depends
// only on the sorted position (rank) of key i.
__global__ void __launch_bounds__(64) mt_kernel(float* __restrict__ mt_out,
                                                uint32_t s0, uint32_t s1) {
    __shared__ uint32_t keys[B_];
    int tid = threadIdx.x;
    for (int j = tid; j < B_; j += 64)
        keys[j] = jax_bits(s0, s1, (uint64_t)j, (uint64_t)B_);
    __syncthreads();
    int i = blockIdx.x * 64 + tid;
    uint32_t ki = keys[i];
    int rank = 0;
    for (int q = 0; q < B_; q++) {
        uint32_t kq = keys[q];
        rank += (kq < ki) || (kq == ki && q < i);
    }
    // NUM_MASK=819, NUM_MASK+NUM_RAND=921
    mt_out[i] = rank < 819 ? 0.0f : (rank < 921 ? 1.0f : 2.0f);
}

// ---------------- Kernel 2: per-row selection -> I (as float) --------------
// order = stable argsort of scores (invalid -> +inf). rank(p) computed by
// pairwise (score, index) lexicographic comparison == stable-sort rank.
__global__ void __launch_bounds__(256) sel_kernel(const int* __restrict__ seq_len,
                                                  float* __restrict__ I_out,
                                                  uint32_t ks0, uint32_t ks1) {
    int b = blockIdx.x;
    int tid = threadIdx.x;
    __shared__ float sc[P_];
    int sl = seq_len[b];
    int n_valid = sl >> 3;                                   // seq_len // 8
    int n_corr = (int)floorf(0.15f * (float)sl / 8.0f);      // f32 exactly as JAX
    for (int p = tid; p < P_; p += 256) {
        float s = __builtin_inff();
        if (p < n_valid) {
            uint32_t bits = jax_bits(ks0, ks1, (uint64_t)b * P_ + p, NSCORE);
            s = u01(bits);
        }
        sc[p] = s;
    }
    // pad slots [n_corr, 76) with -1 (disjoint from rank writes -> no race)
    if (tid < MAXC && tid >= n_corr) I_out[(size_t)b * MAXC + tid] = -1.0f;
    __syncthreads();
    for (int p = tid; p < P_; p += 256) {
        if (p >= n_valid) continue;        // inf rows: rank >= n_valid > n_corr
        float sp = sc[p];
        int rank = 0;
        for (int q = 0; q < n_valid; q++) {
            float sq = sc[q];
            rank += (sq < sp) || (sq == sp && q < p);
        }
        if (rank < n_corr) I_out[(size_t)b * MAXC + rank] = (float)p;
    }
}

// ---------------- Kernel 3: x_out --------------------------------------
// One block per row b. Rebuild the 512-bit selection mask from I (LDS),
// then stream 512*128 floats as float4.
__global__ void __launch_bounds__(256) xout_kernel(const float* __restrict__ x,
                                                    const float* __restrict__ pos,
                                                    const float* __restrict__ wm,
                                                    const float* __restrict__ I_in,
                                                    float* __restrict__ out,
                                                    int t0, uint32_t kr0, uint32_t kr1) {
    int b = blockIdx.x;
    int tid = threadIdx.x;
    __shared__ uint32_t selmask[P_ / 32];
    if (tid < P_ / 32) selmask[tid] = 0u;
    __syncthreads();
    if (tid < MAXC) {
        float v = I_in[(size_t)b * MAXC + tid];
        if (v >= 0.0f) {
            int p = (int)v;
            atomicOr(&selmask[p >> 5], 1u << (p & 31));
        }
    }
    __syncthreads();

    const float4* x4  = (const float4*)x + (size_t)b * (P_ * (K_ / 4));
    float4*       o4  = (float4*)out     + (size_t)b * (P_ * (K_ / 4));
    const float4* p4  = (const float4*)pos;
    const float4* wm4 = (const float4*)wm;

    for (int i = tid; i < P_ * (K_ / 4); i += 256) {
        int p  = i >> 5;       // patch index
        int kq = i & 31;       // float4 index within patch (k = 4*kq)
        bool sel = (selmask[p >> 5] >> (p & 31)) & 1u;
        float4 v;
        if (!sel || t0 == 2) {
            v = x4[i];
        } else if (t0 == 0) {
            float4 a = wm4[kq];
            float4 c = p4[p * (K_ / 4) + kq];
            v.x = a.x + c.x; v.y = a.y + c.y; v.z = a.z + c.z; v.w = a.w + c.w;
        } else { // t0 == 1: rand_vals + pos, generated only where needed
            float4 c = p4[p * (K_ / 4) + kq];
            uint64_t e = (((uint64_t)b * P_ + p) * K_) + (uint64_t)kq * 4;
            v.x = u01(jax_bits(kr0, kr1, e + 0, NRAND)) + c.x;
            v.y = u01(jax_bits(kr0, kr1, e + 1, NRAND)) + c.y;
            v.z = u01(jax_bits(kr0, kr1, e + 2, NRAND)) + c.z;
            v.w = u01(jax_bits(kr0, kr1, e + 3, NRAND)) + c.w;
        }
        o4[i] = v;
    }
}

// ---------------- Host: derive keys (pure function of seed 42) -------------
extern "C" void kernel_launch(void* const* d_in, const int* in_sizes, int n_in,
                              void* d_out, int out_size, void* d_ws, size_t ws_size,
                              hipStream_t stream) {
    (void)in_sizes; (void)n_in; (void)d_ws; (void)ws_size; (void)out_size;
    const float* x   = (const float*)d_in[0];
    const float* pos = (const float*)d_in[1];
    const float* wm  = (const float*)d_in[2];
    const int* seq_len = (const int*)d_in[3];
    float* out = (float*)d_out;

    // key(42) = (0, 42); split into kp, ks, kr; shuffle subkey from split(kp)
    uint32_t kp0, kp1, ks0, ks1, kr0, kr1, sub0, sub1;
#if JAX_PARTITIONABLE
    tf2x32(0u, 42u, 0u, 0u, kp0, kp1);
    tf2x32(0u, 42u, 0u, 1u, ks0, ks1);
    tf2x32(0u, 42u, 0u, 2u, kr0, kr1);
    // split(kp, 2)[1] (fold-like): threefry(kp, (0, 1))
    tf2x32(kp0, kp1, 0u, 1u, sub0, sub1);
#else
    {
        uint32_t a0, b0, a1, b1, a2, b2;
        tf2x32(0u, 42u, 0u, 3u, a0, b0);
        tf2x32(0u, 42u, 1u, 4u, a1, b1);
        tf2x32(0u, 42u, 2u, 5u, a2, b2);
        kp0 = a0; kp1 = a1; ks0 = a2; ks1 = b0; kr0 = b1; kr1 = b2;
        // split(kp,2): counts [0..3] -> pairs (0,2),(1,3); row1 = (f1(0,2), f1(1,3))
        uint32_t c0, d0, c1, d1;
        tf2x32(kp0, kp1, 0u, 2u, c0, d0);
        tf2x32(kp0, kp1, 1u, 3u, c1, d1);
        sub0 = d0; sub1 = d1;
    }
#endif

    // t0 = mask_type[0]: rank of sort_keys[0] among all 1024 (host, deterministic)
    static uint32_t skeys[B_];
    for (int i = 0; i < B_; i++) skeys[i] = jax_bits(sub0, sub1, (uint64_t)i, (uint64_t)B_);
    int rank0 = 0;
    for (int q = 1; q < B_; q++) if (skeys[q] < skeys[0]) rank0++;
    int t0 = rank0 < 819 ? 0 : (rank0 < 921 ? 1 : 2);

    float* I_out  = out + OFF_I;
    float* mt_out = out + OFF_MT;

    hipLaunchKernelGGL(mt_kernel, dim3(B_ / 64), dim3(64), 0, stream, mt_out, sub0, sub1);
    hipLaunchKernelGGL(sel_kernel, dim3(B_), dim3(256), 0, stream, seq_len, I_out, ks0, ks1);
    hipLaunchKernelGGL(xout_kernel, dim3(B_), dim3(256), 0, stream,
                       x, pos, wm, I_out, out, t0, kr0, kr1);
}

// Round 2
// 477.538 us; speedup vs baseline: 1.0641x; 1.0641x over previous
//
#include <hip/hip_runtime.h>
#include <cstdint>
#include <cstring>

// JAX PRNG variant: 1 = jax_threefry_partitionable=True (verified correct R1)
#define JAX_PARTITIONABLE 1

#define B_ 1024
#define P_ 512
#define K_ 128
#define MAXC 76
#define NSCORE 524288ull     // B*P
#define NRAND  67108864ull   // B*P*K
#define OFF_I  ((size_t)B_ * P_ * K_)          // 67108864
#define OFF_MT (OFF_I + (size_t)B_ * MAXC)     // + 77824

typedef float f4 __attribute__((ext_vector_type(4)));

// ---------------- Threefry2x32 (exact JAX schedule) ----------------
__host__ __device__ inline uint32_t rotl32(uint32_t v, int d) {
    return (v << d) | (v >> (32 - d));
}

__host__ __device__ inline void tf2x32(uint32_t k0, uint32_t k1,
                                       uint32_t x0, uint32_t x1,
                                       uint32_t& o0, uint32_t& o1) {
    uint32_t ks2 = k0 ^ k1 ^ 0x1BD11BDAu;
    x0 += k0; x1 += k1;
#define TF_R(r) { x0 += x1; x1 = rotl32(x1, (r)); x1 ^= x0; }
    TF_R(13) TF_R(15) TF_R(26) TF_R(6)
    x0 += k1;  x1 += ks2 + 1u;
    TF_R(17) TF_R(29) TF_R(16) TF_R(24)
    x0 += ks2; x1 += k0 + 2u;
    TF_R(13) TF_R(15) TF_R(26) TF_R(6)
    x0 += k0;  x1 += k1 + 3u;
    TF_R(17) TF_R(29) TF_R(16) TF_R(24)
    x0 += k1;  x1 += ks2 + 4u;
    TF_R(13) TF_R(15) TF_R(26) TF_R(6)
    x0 += ks2; x1 += k0 + 5u;
#undef TF_R
    o0 = x0; o1 = x1;
}

__host__ __device__ inline uint32_t jax_bits(uint32_t k0, uint32_t k1,
                                             uint64_t i, uint64_t n) {
#if JAX_PARTITIONABLE
    (void)n;
    uint32_t o0, o1;
    tf2x32(k0, k1, (uint32_t)(i >> 32), (uint32_t)i, o0, o1);
    return o0 ^ o1;
#else
    uint64_t half = n >> 1;
    uint32_t o0, o1;
    if (i < half) { tf2x32(k0, k1, (uint32_t)i, (uint32_t)(i + half), o0, o1); return o0; }
    tf2x32(k0, k1, (uint32_t)(i - half), (uint32_t)i, o0, o1); return o1;
#endif
}

__device__ inline float u01(uint32_t bits) {
    return __uint_as_float((bits >> 9) | 0x3F800000u) - 1.0f;
}

// ---------------- Kernel 1: mask_type (tiny) ----------------
__global__ void __launch_bounds__(256) mt_kernel(float* __restrict__ mt_out,
                                                 uint32_t s0, uint32_t s1) {
    __shared__ uint32_t keys[B_];
    int tid = threadIdx.x;
    for (int j = tid; j < B_; j += 256)
        keys[j] = jax_bits(s0, s1, (uint64_t)j, (uint64_t)B_);
    __syncthreads();
    int i = blockIdx.x * 256 + tid;
    uint32_t ki = keys[i];
    int rank = 0;
    for (int q = 0; q < B_; q++) {
        uint32_t kq = keys[q];
        rank += (kq < ki) || (kq == ki && q < i);
    }
    mt_out[i] = rank < 819 ? 0.0f : (rank < 921 ? 1.0f : 2.0f);
}

// ---------------- Kernel 2 (fused): selection + I + x_out per row ----------
__global__ void __launch_bounds__(256) fused_kernel(const float* __restrict__ x,
                                                    const float* __restrict__ pos,
                                                    const float* __restrict__ wm,
                                                    const int* __restrict__ seq_len,
                                                    float* __restrict__ out,
                                                    float* __restrict__ I_out,
                                                    int t0,
                                                    uint32_t ks0, uint32_t ks1,
                                                    uint32_t kr0, uint32_t kr1) {
    int b = blockIdx.x;
    int tid = threadIdx.x;
    __shared__ float sc[P_];
    __shared__ uint32_t selmask[P_ / 32];

    int sl = seq_len[b];
    int n_valid = sl >> 3;
    int n_corr = (int)floorf(0.15f * (float)sl / 8.0f);   // f32, exactly as JAX

    if (tid < P_ / 32) selmask[tid] = 0u;
    // scores for this row (2 per thread)
    for (int p = tid; p < P_; p += 256) {
        float s = __builtin_inff();
        if (p < n_valid) {
            uint32_t bits = jax_bits(ks0, ks1, (uint64_t)b * P_ + p, NSCORE);
            s = u01(bits);
        }
        sc[p] = s;
    }
    // pad I slots [n_corr, 76) with -1 (disjoint from rank-indexed writes)
    if (tid < MAXC && tid >= n_corr) I_out[(size_t)b * MAXC + tid] = -1.0f;
    __syncthreads();

    // stable-sort rank via pairwise (score, index) comparison
    for (int p = tid; p < n_valid; p += 256) {
        float sp = sc[p];
        int rank = 0;
        for (int q = 0; q < n_valid; q++) {
            float sq = sc[q];
            rank += (sq < sp) || (sq == sp && q < p);
        }
        if (rank < n_corr) {
            I_out[(size_t)b * MAXC + rank] = (float)p;
            atomicOr(&selmask[p >> 5], 1u << (p & 31));
        }
    }
    __syncthreads();

    // stream the row: 512*32 float4, single-touch -> nontemporal
    const f4* x4  = (const f4*)x + (size_t)b * (P_ * (K_ / 4));
    f4*       o4  = (f4*)out     + (size_t)b * (P_ * (K_ / 4));
    const f4* p4  = (const f4*)pos;                    // reused 1024x -> cached
    const f4* wm4 = (const f4*)wm;

    for (int i = tid; i < P_ * (K_ / 4); i += 256) {
        int p  = i >> 5;       // patch
        int kq = i & 31;       // float4 within patch
        bool sel = (selmask[p >> 5] >> (p & 31)) & 1u;
        f4 v;
        if (!sel || t0 == 2) {
            v = __builtin_nontemporal_load(&x4[i]);
        } else if (t0 == 0) {
            f4 a = wm4[kq];
            f4 c = p4[p * (K_ / 4) + kq];
            v = a + c;
        } else { // t0 == 1
            f4 c = p4[p * (K_ / 4) + kq];
            uint64_t e = (((uint64_t)b * P_ + p) * K_) + (uint64_t)kq * 4;
            v.x = u01(jax_bits(kr0, kr1, e + 0, NRAND)) + c.x;
            v.y = u01(jax_bits(kr0, kr1, e + 1, NRAND)) + c.y;
            v.z = u01(jax_bits(kr0, kr1, e + 2, NRAND)) + c.z;
            v.w = u01(jax_bits(kr0, kr1, e + 3, NRAND)) + c.w;
        }
        __builtin_nontemporal_store(v, &o4[i]);
    }
}

// ---------------- Host ----------------
extern "C" void kernel_launch(void* const* d_in, const int* in_sizes, int n_in,
                              void* d_out, int out_size, void* d_ws, size_t ws_size,
                              hipStream_t stream) {
    (void)in_sizes; (void)n_in; (void)d_ws; (void)ws_size; (void)out_size;
    const float* x   = (const float*)d_in[0];
    const float* pos = (const float*)d_in[1];
    const float* wm  = (const float*)d_in[2];
    const int* seq_len = (const int*)d_in[3];
    float* out = (float*)d_out;

    uint32_t kp0, kp1, ks0, ks1, kr0, kr1, sub0, sub1;
#if JAX_PARTITIONABLE
    tf2x32(0u, 42u, 0u, 0u, kp0, kp1);
    tf2x32(0u, 42u, 0u, 1u, ks0, ks1);
    tf2x32(0u, 42u, 0u, 2u, kr0, kr1);
    tf2x32(kp0, kp1, 0u, 1u, sub0, sub1);   // split(kp,2)[1]
#else
    {
        uint32_t a0, b0, a1, b1, a2, b2;
        tf2x32(0u, 42u, 0u, 3u, a0, b0);
        tf2x32(0u, 42u, 1u, 4u, a1, b1);
        tf2x32(0u, 42u, 2u, 5u, a2, b2);
        kp0 = a0; kp1 = a1; ks0 = a2; ks1 = b0; kr0 = b1; kr1 = b2;
        uint32_t c0, d0, c1, d1;
        tf2x32(kp0, kp1, 0u, 2u, c0, d0);
        tf2x32(kp0, kp1, 1u, 3u, c1, d1);
        sub0 = d0; sub1 = d1;
    }
#endif

    // t0 = mask_type[0]: host-side, pure function of seed 42
    static uint32_t skeys[B_];
    for (int i = 0; i < B_; i++) skeys[i] = jax_bits(sub0, sub1, (uint64_t)i, (uint64_t)B_);
    int rank0 = 0;
    for (int q = 1; q < B_; q++) if (skeys[q] < skeys[0]) rank0++;
    int t0 = rank0 < 819 ? 0 : (rank0 < 921 ? 1 : 2);

    float* I_out  = out + OFF_I;
    float* mt_out = out + OFF_MT;

    hipLaunchKernelGGL(mt_kernel, dim3(B_ / 256), dim3(256), 0, stream, mt_out, sub0, sub1);
    hipLaunchKernelGGL(fused_kernel, dim3(B_), dim3(256), 0, stream,
                       x, pos, wm, seq_len, out, I_out, t0, ks0, ks1, kr0, kr1);
}